// Round 15
// baseline (3243.724 us; speedup 1.0000x reference)
//
#include <hip/hip_runtime.h>
#include <cstdint>
#include <cstddef>

// ---------------------------------------------------------------------------
// ConditionedPNA on MI355X, round 15.
// = round-14 kernel (3.18 ms, absmax 0.0) with the R12 fusion retried at
// 4 nodes/wave: aggpna + scoreK fused into k_aggscore. R12 failed only on
// the VGPR 84->88 occupancy cliff (6->5 waves/SIMD); halving per-node
// register arrays (~30 VGPRs) should land ~60-70 VGPR -> 7-8 waves/SIMD,
// ABOVE the unfused kernel. Per-node fp chains untouched -> bit-exact.
// Saves the scoreK dispatch + a ~50MB/dispatch hidden re-read per layer.
// NOTE: all atomics use pointer-arithmetic form (arr + i) -- the source
// pipeline HTML-decodes "&"+identifier sequences.
// ---------------------------------------------------------------------------

#define NN   50000
#define NEG  1600000
#define NR2  1000
#define NTC  32
#define NMI  10000
#define KSEL 5000u
#define ESEL 160000u
#define KEY_NEG_INF 0x007FFFFFu

// per-batch workspace block offsets (u32 units)
#define OFF_ST    0         // 64   (st[0]=v st[1]=R st[2]=takeTot st[3]=nact st[4]=gtTot st[5]=srcCnt, stF[7]=head)
#define OFF_RELB  64        // 64
#define OFF_BC    128       // 2048
#define OFF_BC2   2176      // 2048
#define OFF_HISTA 4224      // 65536 (pass1)
#define OFF_HISTB 69760     // 65536 (pass0)  [A+B contiguous 131072]
#define OFF_SCORE 135296    // 50000
#define OFF_NSEL  185296    // 50000 (0/1 from selNodes; slot map after rowSnap)
#define OFF_DCNT  235296    // 50000
#define OFF_ROWS  285296    // 50000
#define OFF_CURS  335296    // 50000 (indeg during edge select; csr cursor after)
#define OFF_ACT   385296    // 50000
#define OFF_HID   435296    // 3200000
#define OFF_SRCH  3635296   // 320000 (source snapshot)
#define OFF_ELIST 3955296   // 160000
#define OFF_CSR   4115296   // 160000 (packed (slot<<10)|etype)
#define SBLK      4275296

#define RL(x,k) __int_as_float(__builtin_amdgcn_readlane(__float_as_int(x),(k)))
#define BBASE unsigned* B = WB + (size_t)blockIdx.y * (size_t)sb

__device__ inline unsigned fkey(float f){
  unsigned u = __float_as_uint(f);
  if ((u << 1) == 0u) u = 0u;                    // canonicalize -0 -> +0
  return (u & 0x80000000u) ? ~u : (u | 0x80000000u);
}

__device__ inline float waveSumF(float v){
  #pragma unroll
  for (int d = 1; d < 64; d <<= 1) v += __shfl_xor(v, d);
  return v;
}

__device__ inline void ldsHashAdd(unsigned* hkey, unsigned* hval, unsigned bin, unsigned cnt){
  unsigned h = (bin * 2654435761u) >> 23;        // 9 bits -> 0..511
  while (true){
    unsigned prev = atomicCAS(hkey + h, 0xFFFFFFFFu, bin);
    if (prev == 0xFFFFFFFFu || prev == bin){ atomicAdd(hval + h, cnt); return; }
    h = (h + 1u) & 511u;
  }
}

// ------------------------------- setup kernels ------------------------------

__global__ void k_lastm(const int* __restrict__ all_index, int* __restrict__ lastm){
  int i = blockIdx.x * 256 + threadIdx.x;
  if (i < NMI) atomicMax(lastm + all_index[i], i);
}

__global__ void k_degfull(const int* __restrict__ esrc, unsigned* __restrict__ degf){
  int i = blockIdx.x * 256 + threadIdx.x;
  if (i < NEG) atomicAdd(degf + esrc[i], 1u);
}

// dmean accumulation: per-wave f32 atomicAdd, hardware order (validated)
__global__ void k_dsum(const unsigned* __restrict__ degf, float* __restrict__ gstF){
  int i = blockIdx.x * 256 + threadIdx.x;
  float v = (i < NN) ? logf((float)degf[i] + 1.f) : 0.f;
  v = waveSumF(v);
  if ((threadIdx.x & 63) == 0) atomicAdd(gstF + 4, v);
}

__global__ void k_finalize(float* __restrict__ gstF, const float* __restrict__ b1,
                           const float* __restrict__ w2, const float* __restrict__ b2){
  gstF[5] = gstF[4] / (float)NN;                // dmean
  float s = 0.f;
  for (int m = 0; m < 128; m++) s += fmaxf(b1[m], 0.f) * w2[m];
  gstF[6] = s + b2[0];                          // base score for zero hidden
}

// ----------------------------- per-batch init -------------------------------

__global__ void k_relb(unsigned* WB, long sb, int b0,
                       const int* __restrict__ r_index, const float* __restrict__ hs,
                       const float* __restrict__ rel_table, const float* __restrict__ lw,
                       const float* __restrict__ lb, const float* __restrict__ w1,
                       const float* __restrict__ b1, const float* __restrict__ w2,
                       const float* __restrict__ b2){
  BBASE;
  float* relb = (float*)(B + OFF_RELB);
  float* stF  = (float*)(B + OFF_ST);
  int b = b0 + blockIdx.y;
  int j = threadIdx.x;                          // 64 threads, 1 wave
  int r = r_index[b];
  float acc = lb[j];
  for (int k = 0; k < 64; k++) acc = fmaf(rel_table[(size_t)r*64 + k], lw[(64 + k)*64 + j], acc);
  relb[j] = acc;
  float heur = acc;
  for (int k = 0; k < 64; k++) heur = fmaf(hs[b*64 + k], lw[k*64 + j], heur);
  float x = hs[b*64 + j] * heur;
  float o = 0.f;
  for (int half = 0; half < 2; half++){
    float a = b1[half*64 + j];
    for (int k = 0; k < 64; k++) a = fmaf(__shfl(x, k), w1[k*128 + half*64 + j], a);
    o = fmaf(fmaxf(a, 0.f), w2[half*64 + j], o);
  }
  o = waveSumF(o);
  if (j == 0) stF[7] = o + b2[0];
}

__global__ void k_inithidden(unsigned* WB, long sb, int b0,
                             const int* __restrict__ lastm, const float* __restrict__ ste,
                             const float* __restrict__ hs, const int* __restrict__ h_index){
  BBASE;
  float4* hidden = (float4*)(B + OFF_HID);
  const float4* ste4 = (const float4*)ste;
  const float4* hs4  = (const float4*)hs;
  int b = b0 + blockIdx.y;
  int idx = blockIdx.x * 256 + threadIdx.x;     // grid covers NN*16 exactly
  int n = idx >> 4, j = idx & 15;
  int h = h_index[b];
  float4 v = make_float4(0.f, 0.f, 0.f, 0.f);
  int lm = lastm[n];
  if (lm >= 0) v = ste4[(size_t)lm*16 + j];
  if (n == h)  v = hs4[b*16 + j];
  hidden[idx] = v;
}

__global__ void k_initscore(unsigned* WB, long sb, int b0,
                            const int* __restrict__ h_index, const float* __restrict__ gstF){
  BBASE;
  float* score = (float*)(B + OFF_SCORE);
  unsigned* st = B + OFF_ST;
  float* stF = (float*)st;
  int b = b0 + blockIdx.y;
  int i = blockIdx.x * 256 + threadIdx.x;
  if (i < NN) score[i] = (i == h_index[b]) ? stF[7] : gstF[6];
  if (i == 0){ st[0] = 0u; st[1] = KSEL; }
}

// ------------------------------ top-k machinery -----------------------------

// node histogram (unweighted): 2 leader rounds -> LDS hash -> single-plane flush
__global__ __launch_bounds__(256) void k_hist(unsigned* WB, long sb, int pass){
  BBASE;
  const unsigned* st = B + OFF_ST;
  const float* score = (const float*)(B + OFF_SCORE);
  unsigned* hist = B + ((pass == 1) ? OFF_HISTA : OFF_HISTB);
  __shared__ unsigned hkey[512];
  __shared__ unsigned hval[512];
  for (int t = threadIdx.x; t < 512; t += 256){ hkey[t] = 0xFFFFFFFFu; hval[t] = 0u; }
  __syncthreads();
  int i = blockIdx.x * 256 + threadIdx.x;
  unsigned bin = 0xFFFFFFFFu;
  if (i < NN){
    unsigned k = fkey(score[i]);
    if (pass == 1) bin = k >> 16;
    else if ((k >> 16) == (st[0] >> 16)) bin = k & 0xFFFFu;
  }
  bool active = (bin != 0xFFFFFFFFu);
  int lane = threadIdx.x & 63;
  #pragma unroll
  for (int r = 0; r < 2; r++){
    unsigned long long mask = __ballot((int)active);
    if (mask != 0ull){
      int leader = __ffsll(mask) - 1;
      unsigned lbin = (unsigned)__shfl((int)bin, leader);
      bool same = active && (bin == lbin);
      unsigned long long smask = __ballot((int)same);
      if (lane == leader) ldsHashAdd(hkey, hval, lbin, (unsigned)__popcll(smask));
      if (same) active = false;
    }
  }
  if (active) ldsHashAdd(hkey, hval, bin, 1u);
  __syncthreads();
  for (int t = threadIdx.x; t < 512; t += 256){
    unsigned vv = hval[t];
    if (vv) atomicAdd(hist + hkey[t], vv);
  }
}

// in-degree (from selected sources) accumulation into CURS + st reset
__global__ void k_indegW(unsigned* WB, long sb,
                         const int* __restrict__ esrc, const int* __restrict__ edst){
  BBASE;
  unsigned* st = B + OFF_ST;
  const unsigned* nsel = B + OFF_NSEL;
  unsigned* indeg = B + OFF_CURS;
  int i = blockIdx.x * 256 + threadIdx.x;
  if (i < NEG && nsel[esrc[i]]) atomicAdd(indeg + edst[i], 1u);
  if (i == 0){ st[0] = 0u; st[1] = ESEL; st[2] = 0u; st[3] = 0u; st[4] = 0u; st[5] = 0u; }
}

// weighted node histogram for the edge top-ESEL (weight = indeg)
__global__ __launch_bounds__(256) void k_histW(unsigned* WB, long sb, int pass){
  BBASE;
  const unsigned* st = B + OFF_ST;
  const unsigned* indeg = B + OFF_CURS;
  const float* score = (const float*)(B + OFF_SCORE);
  unsigned* hist = B + ((pass == 1) ? OFF_HISTA : OFF_HISTB);
  __shared__ unsigned hkey[512];
  __shared__ unsigned hval[512];
  for (int t = threadIdx.x; t < 512; t += 256){ hkey[t] = 0xFFFFFFFFu; hval[t] = 0u; }
  __syncthreads();
  int i = blockIdx.x * 256 + threadIdx.x;
  unsigned w = (i < NN) ? indeg[i] : 0u;
  if (w){
    unsigned k = fkey(score[i]);
    unsigned bin = 0xFFFFFFFFu;
    if (pass == 1) bin = k >> 16;
    else if ((k >> 16) == (st[0] >> 16)) bin = k & 0xFFFFu;
    if (bin != 0xFFFFFFFFu) ldsHashAdd(hkey, hval, bin, w);
  }
  __syncthreads();
  for (int t = threadIdx.x; t < 512; t += 256){
    unsigned vv = hval[t];
    if (vv) atomicAdd(hist + hkey[t], vv);
  }
}

// single block per batch: find digit containing the R-th largest; update st.
__global__ __launch_bounds__(1024) void k_pick16(unsigned* WB, long sb, int pass){
  BBASE;
  unsigned* st = B + OFF_ST;
  const unsigned* hist = B + ((pass == 1) ? OFF_HISTA : OFF_HISTB);
  __shared__ unsigned csum[1024];
  __shared__ unsigned sc[1024];
  int t = threadIdx.x;
  unsigned R = st[1];
  unsigned s = 0;
  {
    const unsigned* hp = hist + (unsigned)t * 64u;
    for (int b = 0; b < 64; b++) s += hp[b];
  }
  csum[t] = s; sc[t] = s; __syncthreads();
  for (int d = 1; d < 1024; d <<= 1){
    unsigned v = (t >= d) ? sc[t - d] : 0u;
    __syncthreads();
    sc[t] += v;
    __syncthreads();
  }
  unsigned total = sc[1023];
  unsigned above = total - sc[t];               // keys in higher chunks
  unsigned cs = csum[t];
  if (above < R && above + cs >= R){
    unsigned cum = above;
    for (int b = 63; b >= 0; b--){
      unsigned c = hist[(unsigned)(t*64 + b)];
      if (cum + c >= R){
        unsigned bstar = (unsigned)(t*64 + b);
        if (pass == 1) st[0] = bstar << 16; else st[0] = st[0] | bstar;
        st[1] = R - cum;
        break;
      }
      cum += c;
    }
  }
  if (t == 0 && total < R){                     // threshold lands in -inf bin
    if (pass == 1) st[0] = KEY_NEG_INF & 0xFFFF0000u;
    else           st[0] = st[0] | 0xFFFFu;
    st[1] = R - total;
  }
}

// per-block counts of (eq, gt) vs threshold; zeroes hist buffers AND dcnt.
// mode 0: node keys. mode 1: edge keys recomputed on the fly.
__global__ __launch_bounds__(1024) void k_countEq(unsigned* WB, long sb, int mode, int n,
                                                  const int* __restrict__ esrc,
                                                  const int* __restrict__ edst){
  BBASE;
  unsigned* hz = B + OFF_HISTA;                  // A+B contiguous: 131072 u32
  for (unsigned j = blockIdx.x * 1024u + threadIdx.x; j < 131072u; j += gridDim.x * 1024u)
    hz[j] = 0u;
  unsigned* dcnt = B + OFF_DCNT;
  const unsigned* st = B + OFF_ST;
  const unsigned* nsel = B + OFF_NSEL;
  const float* score = (const float*)(B + OFF_SCORE);
  unsigned* bcE = B + OFF_BC;
  unsigned* bcG = B + OFF_BC2;
  int i = blockIdx.x * 1024 + threadIdx.x;
  if (i < NN) dcnt[i] = 0u;
  unsigned v = st[0];
  unsigned k = 0u;
  if (i < n){
    if (mode) k = nsel[esrc[i]] ? fkey(score[edst[i]]) : KEY_NEG_INF;
    else      k = fkey(score[i]);
  }
  bool eq = (i < n) && (k == v);
  bool gt = (i < n) && (k > v);
  unsigned long long ebal = __ballot((int)eq);
  unsigned long long gbal = __ballot((int)gt);
  __shared__ unsigned wshE[16];
  __shared__ unsigned wshG[16];
  int wid = threadIdx.x >> 6, lane = threadIdx.x & 63;
  if (lane == 0){ wshE[wid] = (unsigned)__popcll(ebal); wshG[wid] = (unsigned)__popcll(gbal); }
  __syncthreads();
  if (threadIdx.x == 0){
    unsigned te = 0, tg = 0;
    for (int w = 0; w < 16; w++){ te += wshE[w]; tg += wshG[w]; }
    bcE[blockIdx.x] = te; bcG[blockIdx.x] = tg;
  }
}

__global__ __launch_bounds__(1024) void k_scanBlocks(unsigned* WB, long sb, int nbk){
  BBASE;
  unsigned* blockcnt = B + OFF_BC;
  __shared__ unsigned sc[2048];
  int t = threadIdx.x;
  unsigned a  = (t < nbk) ? blockcnt[t] : 0u;
  unsigned b2 = (1024 + t < nbk) ? blockcnt[1024 + t] : 0u;
  sc[t] = a; sc[1024 + t] = b2; __syncthreads();
  for (int d = 1; d < 2048; d <<= 1){
    unsigned v1 = (t >= d) ? sc[t - d] : 0u;
    unsigned v2 = (1024 + t >= d) ? sc[1024 + t - d] : 0u;
    __syncthreads();
    sc[t] += v1; sc[1024 + t] += v2;
    __syncthreads();
  }
  if (t < nbk) blockcnt[t] = sc[t] - a;             // exclusive
  if (1024 + t < nbk) blockcnt[1024 + t] = sc[1024 + t] - b2;
}

// dual scan (eq + gt) for edge compaction; also computes st[2], st[4]
__global__ __launch_bounds__(1024) void k_scanBlocks2(unsigned* WB, long sb, int nbk){
  BBASE;
  unsigned* st = B + OFF_ST;
  unsigned* bcE = B + OFF_BC;
  unsigned* bcG = B + OFF_BC2;
  __shared__ unsigned se[2048];
  __shared__ unsigned sg[2048];
  int t = threadIdx.x;
  unsigned e0 = (t < nbk) ? bcE[t] : 0u;
  unsigned e1 = (1024 + t < nbk) ? bcE[1024 + t] : 0u;
  unsigned g0 = (t < nbk) ? bcG[t] : 0u;
  unsigned g1 = (1024 + t < nbk) ? bcG[1024 + t] : 0u;
  se[t] = e0; se[1024 + t] = e1; sg[t] = g0; sg[1024 + t] = g1;
  __syncthreads();
  for (int d = 1; d < 2048; d <<= 1){
    unsigned a1 = (t >= d) ? se[t - d] : 0u;
    unsigned a2 = (1024 + t >= d) ? se[1024 + t - d] : 0u;
    unsigned c1 = (t >= d) ? sg[t - d] : 0u;
    unsigned c2 = (1024 + t >= d) ? sg[1024 + t - d] : 0u;
    __syncthreads();
    se[t] += a1; se[1024 + t] += a2; sg[t] += c1; sg[1024 + t] += c2;
    __syncthreads();
  }
  if (t < nbk) bcE[t] = se[t] - e0;
  if (1024 + t < nbk) bcE[1024 + t] = se[1024 + t] - e1;
  if (t < nbk) bcG[t] = sg[t] - g0;
  if (1024 + t < nbk) bcG[1024 + t] = sg[1024 + t] - g1;
  if (t == 0){
    unsigned gtTot = sg[2047];
    st[4] = gtTot;
    st[2] = gtTot + ((st[0] > KEY_NEG_INF) ? st[1] : 0u);  // R' <= eqTot always
  }
}

// node selection; also zeroes CURS (used as indeg accumulator next)
__global__ __launch_bounds__(1024) void k_selNodes(unsigned* WB, long sb){
  BBASE;
  const unsigned* st = B + OFF_ST;
  const unsigned* blockcnt = B + OFF_BC;
  const float* score = (const float*)(B + OFF_SCORE);
  unsigned* nsel = B + OFF_NSEL;
  unsigned* curs = B + OFF_CURS;
  int i = blockIdx.x * 1024 + threadIdx.x;
  if (i < NN) curs[i] = 0u;
  unsigned v = st[0], R = st[1];
  unsigned k = (i < NN) ? fkey(score[i]) : 0u;
  bool eq = (i < NN) && (k == v);
  unsigned long long bal = __ballot((int)eq);
  __shared__ unsigned wsh[16];
  int wid = threadIdx.x >> 6, lane = threadIdx.x & 63;
  if (lane == 0) wsh[wid] = (unsigned)__popcll(bal);
  __syncthreads();
  unsigned woff = 0;
  for (int w = 0; w < wid; w++) woff += wsh[w];
  unsigned lpre = (unsigned)__popcll(bal & ((1ull << lane) - 1ull));
  unsigned rank = blockcnt[blockIdx.x] + woff + lpre;
  if (i < NN) nsel[i] = (k > v || (eq && rank < R)) ? 1u : 0u;
}

// scan-based edge compaction (keys recomputed; deterministic);
// accumulates dcnt[dst] for taken edges (dcnt zeroed by k_countEq)
__global__ __launch_bounds__(1024) void k_selEdgesCompact(unsigned* WB, long sb,
                                                          const int* __restrict__ esrc,
                                                          const int* __restrict__ edst){
  BBASE;
  const unsigned* st = B + OFF_ST;
  const unsigned* bcE = B + OFF_BC;
  const unsigned* bcG = B + OFF_BC2;
  const unsigned* nsel = B + OFF_NSEL;
  const float* score = (const float*)(B + OFF_SCORE);
  unsigned* elist = B + OFF_ELIST;
  unsigned* dcnt = B + OFF_DCNT;
  int i = blockIdx.x * 1024 + threadIdx.x;
  unsigned v = st[0], R = st[1], gtTot = st[4];
  unsigned k = 0u;
  if (i < NEG) k = nsel[esrc[i]] ? fkey(score[edst[i]]) : KEY_NEG_INF;
  bool eq = (i < NEG) && (k == v);
  bool gt = (i < NEG) && (k > v);                   // gt implies finite key
  unsigned long long ebal = __ballot((int)eq);
  unsigned long long gbal = __ballot((int)gt);
  __shared__ unsigned wshE[16];
  __shared__ unsigned wshG[16];
  int wid = threadIdx.x >> 6, lane = threadIdx.x & 63;
  if (lane == 0){ wshE[wid] = (unsigned)__popcll(ebal); wshG[wid] = (unsigned)__popcll(gbal); }
  __syncthreads();
  unsigned eoff = 0, goff = 0;
  for (int w = 0; w < 16 && w < wid; w++){ eoff += wshE[w]; goff += wshG[w]; }
  unsigned long long ltm = (1ull << lane) - 1ull;
  if (gt){
    elist[bcG[blockIdx.x] + goff + (unsigned)__popcll(gbal & ltm)] = (unsigned)i;
    atomicAdd(dcnt + edst[i], 1u);
  }
  if (eq){
    unsigned rank = bcE[blockIdx.x] + eoff + (unsigned)__popcll(ebal & ltm);
    if (v > KEY_NEG_INF && rank < R){
      elist[gtTot + rank] = (unsigned)i;
      atomicAdd(dcnt + edst[i], 1u);
    }
  }
}

// ------------------------------- CSR build ----------------------------------

__global__ __launch_bounds__(1024) void k_blocksumsInt(unsigned* WB, long sb){
  BBASE;
  const unsigned* dcnt = B + OFF_DCNT;
  unsigned* blockcnt = B + OFF_BC;
  int i = blockIdx.x * 1024 + threadIdx.x;
  unsigned v = (i < NN) ? dcnt[i] : 0u;
  #pragma unroll
  for (int d = 1; d < 64; d <<= 1) v += (unsigned)__shfl_xor((int)v, d);
  __shared__ unsigned wsh[16];
  int wid = threadIdx.x >> 6, lane = threadIdx.x & 63;
  if (lane == 0) wsh[wid] = v;
  __syncthreads();
  if (threadIdx.x == 0){
    unsigned tot = 0;
    for (int w = 0; w < 16; w++) tot += wsh[w];
    blockcnt[blockIdx.x] = tot;
  }
}

// row starts + cursor + ACTIVE list + source snapshot (merged)
__global__ __launch_bounds__(1024) void k_rowSnap(unsigned* WB, long sb){
  BBASE;
  unsigned* st = B + OFF_ST;
  const unsigned* dcnt = B + OFF_DCNT;
  const unsigned* blockcnt = B + OFF_BC;
  unsigned* rowstart = B + OFF_ROWS;
  unsigned* curs = B + OFF_CURS;
  unsigned* actl = B + OFF_ACT;
  unsigned* srcmap = B + OFF_NSEL;
  const float* score = (const float*)(B + OFF_SCORE);
  const float* hidden = (const float*)(B + OFF_HID);
  float* srch = (float*)(B + OFF_SRCH);
  int i = blockIdx.x * 1024 + threadIdx.x;
  int wid = threadIdx.x >> 6, lane = threadIdx.x & 63;
  unsigned d = (i < NN) ? dcnt[i] : 0u;
  unsigned v = d;
  #pragma unroll
  for (int dl = 1; dl < 64; dl <<= 1){
    unsigned t2 = (unsigned)__shfl_up((int)v, dl);
    if (lane >= dl) v += t2;
  }
  bool act = (i < NN) && (d > 0u);
  unsigned long long abal = __ballot((int)act);
  __shared__ unsigned wsh[16];
  __shared__ unsigned awsh[16];
  __shared__ unsigned abase;
  if (lane == 63) wsh[wid] = v;
  if (lane == 0) awsh[wid] = (unsigned)__popcll(abal);
  __syncthreads();
  if (threadIdx.x == 0){
    unsigned tot = 0;
    for (int w = 0; w < 16; w++) tot += awsh[w];
    abase = atomicAdd(st + 3, tot);
  }
  unsigned woff = 0, aoff = 0;
  for (int w = 0; w < wid; w++){ woff += wsh[w]; aoff += awsh[w]; }
  __syncthreads();
  unsigned excl = blockcnt[blockIdx.x] + woff + (v - d);
  if (i < NN){ rowstart[i] = excl; curs[i] = excl; }
  if (act) actl[abase + aoff + (unsigned)__popcll(abal & ((1ull << lane) - 1ull))] = (unsigned)i;

  // ---- snap part: each wave handles its 64 nodes (disjoint arrays above)
  int base = i - lane;                        // wave's node base
  if (base >= NN) return;
  bool sel = (i < NN) && (srcmap[i] != 0u);
  unsigned long long bal = __ballot((int)sel);
  if (bal == 0ull) return;
  unsigned slotbase = 0;
  if (lane == 0) slotbase = atomicAdd(st + 5, (unsigned)__popcll(bal));
  slotbase = (unsigned)__shfl((int)slotbase, 0);
  unsigned long long m2 = bal;
  unsigned idx = 0;
  while (m2){
    int j = __ffsll(m2) - 1;
    m2 = m2 - (m2 bitand (0ull - m2));        // clear lowest set bit (entity-safe)
    int node = base + j;
    unsigned slot = slotbase + idx; idx++;
    if (lane == 0) srcmap[node] = slot;
    float g = 1.f / (1.f + expf(-score[node]));   // same formula as before
    srch[(size_t)slot*64 + lane] = g * hidden[(size_t)node*64 + lane];
  }
}

// scatter packed (slot<<10)|etype into CSR (needs srcmap from k_rowSnap)
__global__ void k_scatter(unsigned* WB, long sb, const int* __restrict__ esrc,
                          const int* __restrict__ edst, const int* __restrict__ etype){
  BBASE;
  const unsigned* st = B + OFF_ST;
  const unsigned* elist = B + OFF_ELIST;
  const unsigned* srcmap = B + OFF_NSEL;
  unsigned* curs = B + OFF_CURS;
  unsigned* csr = B + OFF_CSR;
  unsigned i = blockIdx.x * 256 + threadIdx.x;
  if (i < st[2]){
    unsigned e = elist[i];
    unsigned slot = srcmap[esrc[e]];
    unsigned pk = (slot << 10) | (unsigned)etype[e];
    unsigned pos = atomicAdd(curs + edst[e], 1u);
    csr[pos] = pk;
  }
}

// ----- fused aggregation + PNA update + rescore, 4 nodes/wave (low VGPR) ----

__global__ __launch_bounds__(256) void k_aggscore(unsigned* WB, long sb,
    const float* __restrict__ relw, const float* __restrict__ pw,
    const float* __restrict__ pb, const float* __restrict__ gstF, int l,
    const float* __restrict__ lw, const float* __restrict__ w1,
    const float* __restrict__ b1, const float* __restrict__ w2,
    const float* __restrict__ b2){
  BBASE;
  unsigned* st = B + OFF_ST;
  if (blockIdx.x == 0 && threadIdx.x == 0){ st[0] = 0u; st[1] = KSEL; }  // next node topk
  const unsigned* actl = B + OFF_ACT;
  const unsigned* dcnt = B + OFF_DCNT;
  const unsigned* rows = B + OFF_ROWS;
  const unsigned* csr = B + OFF_CSR;
  const float* srch = (const float*)(B + OFF_SRCH);
  float* hidden = (float*)(B + OFF_HID);
  const float* relb = (const float*)(B + OFF_RELB);
  float* score = (float*)(B + OFF_SCORE);
  const float* relw_l = relw + (size_t)l * NR2 * 64;
  const float* pw_l = pw + (size_t)l * 768 * 64;

  int wv = (blockIdx.x * 256 + threadIdx.x) >> 6;
  int lane = threadIdx.x & 63;
  unsigned nact = st[3];
  unsigned slot0 = (unsigned)wv * 4u;
  if (slot0 >= nact) return;

  int node[4];
  float aggm[4], aggx[4], aggn[4], aggs[4];   // mean, max, min, std
  float ampv[4], attv[4];
  #pragma unroll
  for (int n = 0; n < 4; n++){
    unsigned s = slot0 + (unsigned)n;
    node[n] = (s < nact) ? (int)actl[s] : -1;
  }
  float dmean = gstF[5];
  #pragma unroll
  for (int n = 0; n < 4; n++){
    float sm_ = 0.f, sq_ = 0.f;
    float mx_ = -__builtin_huge_valf(), mn_ = __builtin_huge_valf();
    float dv = 0.f;
    if (node[n] >= 0){
      unsigned cnt = dcnt[node[n]], rs = rows[node[n]];
      dv = (float)cnt;
      for (unsigned ii = 0; ii < cnt; ii++){
        unsigned pk = csr[rs + ii];
        float m = srch[(size_t)(pk >> 10)*64 + lane] * relw_l[(size_t)(pk & 1023u)*64 + lane];
        sm_ += m; sq_ = fmaf(m, m, sq_);
        mx_ = fmaxf(mx_, m); mn_ = fminf(mn_, m);
      }
    }
    if (node[n] >= 0){
      float degc = fmaxf(dv, 1.f);
      float me = sm_ / degc;
      float qv = sq_ / degc;
      aggm[n] = me;
      aggs[n] = sqrtf(fmaxf(qv - me*me, 0.f) + 1e-6f);
      aggx[n] = mx_; aggn[n] = mn_;
      float logd = logf(dv + 1.f);
      ampv[n] = logd / dmean;
      attv[n] = dmean / fmaxf(logd, 1e-6f);
    } else { aggm[n] = 0.f; aggs[n] = 0.f; aggx[n] = 0.f; aggn[n] = 0.f; ampv[n] = 0.f; attv[n] = 0.f; }
  }
  float bias = pb[(size_t)l*64 + lane];
  float acc[4];
  #pragma unroll
  for (int n = 0; n < 4; n++) acc[n] = bias;
  for (int c = 0; c < 12; c++){
    int a = c / 3, s = c - a*3;
    float wreg[64];
    #pragma unroll
    for (int k = 0; k < 64; k++) wreg[k] = pw_l[(size_t)(c*64 + k)*64 + lane];
    float fv[4];
    #pragma unroll
    for (int n = 0; n < 4; n++){
      float v = 0.f;
      if (node[n] >= 0){
        if (a == 0)      v = aggm[n];
        else if (a == 1) v = aggx[n];
        else if (a == 2) v = aggn[n];
        else             v = aggs[n];
        float scaler = (s == 0) ? 1.f : ((s == 1) ? ampv[n] : attv[n]);
        v *= scaler;
      }
      fv[n] = v;
    }
    #pragma unroll
    for (int k = 0; k < 64; k++){
      float w = wreg[k];
      #pragma unroll
      for (int n = 0; n < 4; n++) acc[n] = fmaf(RL(fv[n], k), w, acc[n]);
    }
  }
  // hidden update; keep new value in registers for the score MLP
  float hidv[4];
  #pragma unroll
  for (int n = 0; n < 4; n++){
    if (node[n] >= 0){
      size_t off = (size_t)node[n]*64 + lane;
      float nv = hidden[off] + acc[n];
      hidden[off] = nv;
      hidv[n] = nv;
    } else hidv[n] = 0.f;
  }

  // ---- score MLP (bit-identical to the former k_scoreK, 4 nodes) ----
  float wreg[64];
  #pragma unroll
  for (int k = 0; k < 64; k++) wreg[k] = lw[k*64 + lane];
  float relbv = relb[lane];
  float hv[4];
  #pragma unroll
  for (int n = 0; n < 4; n++) hv[n] = relbv;
  #pragma unroll
  for (int k = 0; k < 64; k++){
    float w = wreg[k];
    #pragma unroll
    for (int n = 0; n < 4; n++) hv[n] = fmaf(RL(hidv[n], k), w, hv[n]);
  }
  float xv[4];
  #pragma unroll
  for (int n = 0; n < 4; n++) xv[n] = hidv[n] * hv[n];
  float outv[4];
  #pragma unroll
  for (int n = 0; n < 4; n++) outv[n] = 0.f;
  for (int half = 0; half < 2; half++){
    #pragma unroll
    for (int k = 0; k < 64; k++) wreg[k] = w1[k*128 + half*64 + lane];
    float a[4];
    float b1l = b1[half*64 + lane];
    #pragma unroll
    for (int n = 0; n < 4; n++) a[n] = b1l;
    #pragma unroll
    for (int k = 0; k < 64; k++){
      float w = wreg[k];
      #pragma unroll
      for (int n = 0; n < 4; n++) a[n] = fmaf(RL(xv[n], k), w, a[n]);
    }
    float w2l = w2[half*64 + lane];
    #pragma unroll
    for (int n = 0; n < 4; n++) outv[n] = fmaf(fmaxf(a[n], 0.f), w2l, outv[n]);
  }
  float b2v = b2[0];
  #pragma unroll
  for (int n = 0; n < 4; n++){
    float r = waveSumF(outv[n]);
    if (lane == 0 && node[n] >= 0) score[node[n]] = r + b2v;
  }
}

__global__ void k_out(unsigned* WB, long sb, int b0,
                      const int* __restrict__ t_index, float* __restrict__ out){
  BBASE;
  const float* score = (const float*)(B + OFF_SCORE);
  int b = b0 + blockIdx.y;
  int t = threadIdx.x;
  if (t < NTC) out[b*NTC + t] = score[t_index[b*NTC + t]];
}

// ------------------------------- launcher -----------------------------------

extern "C" void kernel_launch(void* const* d_in, const int* in_sizes, int n_in,
                              void* d_out, int out_size, void* d_ws, size_t ws_size,
                              hipStream_t stream){
  (void)in_sizes; (void)n_in; (void)out_size;
  const int*   h_index  = (const int*)d_in[0];
  const int*   r_index  = (const int*)d_in[1];
  const int*   t_index  = (const int*)d_in[2];
  const int*   all_idx  = (const int*)d_in[3];
  const int*   esrc     = (const int*)d_in[4];
  const int*   edst     = (const int*)d_in[5];
  const int*   etype    = (const int*)d_in[6];
  const float* hs       = (const float*)d_in[7];
  const float* ste      = (const float*)d_in[8];
  const float* rel_tab  = (const float*)d_in[9];
  const float* lw       = (const float*)d_in[10];
  const float* lb       = (const float*)d_in[11];
  const float* w1       = (const float*)d_in[12];
  const float* b1       = (const float*)d_in[13];
  const float* w2       = (const float*)d_in[14];
  const float* b2       = (const float*)d_in[15];
  const float* relw     = (const float*)d_in[16];
  const float* pna_w    = (const float*)d_in[17];
  const float* pna_b    = (const float*)d_in[18];
  float* out = (float*)d_out;

  unsigned* W = (unsigned*)d_ws;
  int*      LASTM = (int*)W;                    // 50000
  unsigned* DEGF  = W + 50000;                  // 50000
  float*    GSTF  = (float*)(W + 100000);       // 64
  unsigned* WB    = W + 100064;                 // batch blocks

  size_t needB = (size_t)(100064 + 4*(size_t)SBLK) * 4u;
  int nb; long sb; int nseq;
  if (ws_size >= needB){ nb = 4; sb = SBLK; nseq = 1; }
  else                 { nb = 1; sb = 0;    nseq = 4; }

  (void)hipMemsetAsync(W + 100000, 0, 64 * 4, stream);          // GSTF
  (void)hipMemsetAsync(LASTM, 0xFF, NN * 4, stream);
  (void)hipMemsetAsync(DEGF, 0, NN * 4, stream);
  for (int q = 0; q < nb; q++)
    (void)hipMemsetAsync(WB + (size_t)q*SBLK + OFF_HISTA, 0, 131072 * 4, stream);

  const int GB_E256  = (NEG + 255) / 256;       // 6250
  const int GB_N256  = (NN + 255) / 256;        // 196
  const int GB_N1024 = (NN + 1023) / 1024;      // 49
  const int GB_E1024 = (NEG + 1023) / 1024;     // 1563
  const int GB_H4    = (NN * 16) / 256;         // 3125 (float4 rows)
  const int GB_A4    = (NN + 15) / 16;          // 3125 (4 waves x 4 slots / block)
  const int GB_ES    = (int)(ESEL / 256);       // 625

  k_lastm<<<(NMI + 255) / 256, 256, 0, stream>>>(all_idx, LASTM);
  k_degfull<<<GB_E256, 256, 0, stream>>>(esrc, DEGF);
  k_dsum<<<GB_N256, 256, 0, stream>>>(DEGF, GSTF);
  k_finalize<<<1, 1, 0, stream>>>(GSTF, b1, w2, b2);

  for (int q = 0; q < nseq; q++){
    int b0 = (nb == 4) ? 0 : q;
    k_relb<<<dim3(1, nb), 64, 0, stream>>>(WB, sb, b0, r_index, hs, rel_tab, lw, lb, w1, b1, w2, b2);
    k_inithidden<<<dim3(GB_H4, nb), 256, 0, stream>>>(WB, sb, b0, LASTM, ste, hs, h_index);
    k_initscore<<<dim3(GB_N256, nb), 256, 0, stream>>>(WB, sb, b0, h_index, GSTF);

    for (int l = 0; l < 3; l++){
      // ---- node top-K
      k_hist<<<dim3(GB_N256, nb), 256, 0, stream>>>(WB, sb, 1);
      k_pick16<<<dim3(1, nb), 1024, 0, stream>>>(WB, sb, 1);
      k_hist<<<dim3(GB_N256, nb), 256, 0, stream>>>(WB, sb, 0);
      k_pick16<<<dim3(1, nb), 1024, 0, stream>>>(WB, sb, 0);
      k_countEq<<<dim3(GB_N1024, nb), 1024, 0, stream>>>(WB, sb, 0, NN, esrc, edst);
      k_scanBlocks<<<dim3(1, nb), 1024, 0, stream>>>(WB, sb, GB_N1024);
      k_selNodes<<<dim3(GB_N1024, nb), 1024, 0, stream>>>(WB, sb);      // + zeroes CURS
      // ---- edge top-ESEL as weighted node top-k
      k_indegW<<<dim3(GB_E256, nb), 256, 0, stream>>>(WB, sb, esrc, edst);
      k_histW<<<dim3(GB_N256, nb), 256, 0, stream>>>(WB, sb, 1);
      k_pick16<<<dim3(1, nb), 1024, 0, stream>>>(WB, sb, 1);
      k_histW<<<dim3(GB_N256, nb), 256, 0, stream>>>(WB, sb, 0);
      k_pick16<<<dim3(1, nb), 1024, 0, stream>>>(WB, sb, 0);
      k_countEq<<<dim3(GB_E1024, nb), 1024, 0, stream>>>(WB, sb, 1, NEG, esrc, edst);
      k_scanBlocks2<<<dim3(1, nb), 1024, 0, stream>>>(WB, sb, GB_E1024);
      k_selEdgesCompact<<<dim3(GB_E1024, nb), 1024, 0, stream>>>(WB, sb, esrc, edst);
      // ---- CSR rows + active compaction + snapshot (merged) + scatter
      k_blocksumsInt<<<dim3(GB_N1024, nb), 1024, 0, stream>>>(WB, sb);
      k_scanBlocks<<<dim3(1, nb), 1024, 0, stream>>>(WB, sb, GB_N1024);
      k_rowSnap<<<dim3(GB_N1024, nb), 1024, 0, stream>>>(WB, sb);
      k_scatter<<<dim3(GB_ES, nb), 256, 0, stream>>>(WB, sb, esrc, edst, etype);
      // ---- fused aggregate + PNA + rescore (4 nodes/wave, low VGPR)
      k_aggscore<<<dim3(GB_A4, nb), 256, 0, stream>>>(WB, sb, relw, pna_w, pna_b, GSTF, l,
                                                      lw, w1, b1, w2, b2);
    }
    k_out<<<dim3(1, nb), 32, 0, stream>>>(WB, sb, b0, t_index, out);
  }
}

// Round 16
// 3167.653 us; speedup vs baseline: 1.0240x; 1.0240x over previous
//
#include <hip/hip_runtime.h>
#include <cstdint>
#include <cstddef>

// ---------------------------------------------------------------------------
// ConditionedPNA on MI355X, round 16 = round-14 kernel verbatim (best:
// 3.18 ms, absmax 0.0). R15's 4-nodes/wave fusion regressed (VGPR 80 ->
// still 6 waves/SIMD, but halved weight-load amortization). Both fusion
// variants (R12: 8n/wave busts VGPR cliff; R15: 4n/wave wastes weight
// traffic) are dominated by the split aggpna/scoreK at 6 waves/SIMD.
// NOTE: all atomics use pointer-arithmetic form (arr + i) -- the source
// pipeline HTML-decodes "&"+identifier sequences.
// ---------------------------------------------------------------------------

#define NN   50000
#define NEG  1600000
#define NR2  1000
#define NTC  32
#define NMI  10000
#define KSEL 5000u
#define ESEL 160000u
#define KEY_NEG_INF 0x007FFFFFu

// per-batch workspace block offsets (u32 units)
#define OFF_ST    0         // 64   (st[0]=v st[1]=R st[2]=takeTot st[3]=nact st[4]=gtTot st[5]=srcCnt, stF[7]=head)
#define OFF_RELB  64        // 64
#define OFF_BC    128       // 2048
#define OFF_BC2   2176      // 2048
#define OFF_HISTA 4224      // 65536 (pass1)
#define OFF_HISTB 69760     // 65536 (pass0)  [A+B contiguous 131072]
#define OFF_SCORE 135296    // 50000
#define OFF_NSEL  185296    // 50000 (0/1 from selNodes; slot map after rowSnap)
#define OFF_DCNT  235296    // 50000
#define OFF_ROWS  285296    // 50000
#define OFF_CURS  335296    // 50000 (indeg during edge select; csr cursor after)
#define OFF_ACT   385296    // 50000
#define OFF_HID   435296    // 3200000
#define OFF_SRCH  3635296   // 320000 (source snapshot)
#define OFF_ELIST 3955296   // 160000
#define OFF_CSR   4115296   // 160000 (packed (slot<<10)|etype)
#define SBLK      4275296

#define RL(x,k) __int_as_float(__builtin_amdgcn_readlane(__float_as_int(x),(k)))
#define BBASE unsigned* B = WB + (size_t)blockIdx.y * (size_t)sb

__device__ inline unsigned fkey(float f){
  unsigned u = __float_as_uint(f);
  if ((u << 1) == 0u) u = 0u;                    // canonicalize -0 -> +0
  return (u & 0x80000000u) ? ~u : (u | 0x80000000u);
}

__device__ inline float waveSumF(float v){
  #pragma unroll
  for (int d = 1; d < 64; d <<= 1) v += __shfl_xor(v, d);
  return v;
}

__device__ inline void ldsHashAdd(unsigned* hkey, unsigned* hval, unsigned bin, unsigned cnt){
  unsigned h = (bin * 2654435761u) >> 23;        // 9 bits -> 0..511
  while (true){
    unsigned prev = atomicCAS(hkey + h, 0xFFFFFFFFu, bin);
    if (prev == 0xFFFFFFFFu || prev == bin){ atomicAdd(hval + h, cnt); return; }
    h = (h + 1u) & 511u;
  }
}

// ------------------------------- setup kernels ------------------------------

__global__ void k_lastm(const int* __restrict__ all_index, int* __restrict__ lastm){
  int i = blockIdx.x * 256 + threadIdx.x;
  if (i < NMI) atomicMax(lastm + all_index[i], i);
}

__global__ void k_degfull(const int* __restrict__ esrc, unsigned* __restrict__ degf){
  int i = blockIdx.x * 256 + threadIdx.x;
  if (i < NEG) atomicAdd(degf + esrc[i], 1u);
}

// dmean accumulation: per-wave f32 atomicAdd, hardware order (validated)
__global__ void k_dsum(const unsigned* __restrict__ degf, float* __restrict__ gstF){
  int i = blockIdx.x * 256 + threadIdx.x;
  float v = (i < NN) ? logf((float)degf[i] + 1.f) : 0.f;
  v = waveSumF(v);
  if ((threadIdx.x & 63) == 0) atomicAdd(gstF + 4, v);
}

__global__ void k_finalize(float* __restrict__ gstF, const float* __restrict__ b1,
                           const float* __restrict__ w2, const float* __restrict__ b2){
  gstF[5] = gstF[4] / (float)NN;                // dmean
  float s = 0.f;
  for (int m = 0; m < 128; m++) s += fmaxf(b1[m], 0.f) * w2[m];
  gstF[6] = s + b2[0];                          // base score for zero hidden
}

// ----------------------------- per-batch init -------------------------------

__global__ void k_relb(unsigned* WB, long sb, int b0,
                       const int* __restrict__ r_index, const float* __restrict__ hs,
                       const float* __restrict__ rel_table, const float* __restrict__ lw,
                       const float* __restrict__ lb, const float* __restrict__ w1,
                       const float* __restrict__ b1, const float* __restrict__ w2,
                       const float* __restrict__ b2){
  BBASE;
  float* relb = (float*)(B + OFF_RELB);
  float* stF  = (float*)(B + OFF_ST);
  int b = b0 + blockIdx.y;
  int j = threadIdx.x;                          // 64 threads, 1 wave
  int r = r_index[b];
  float acc = lb[j];
  for (int k = 0; k < 64; k++) acc = fmaf(rel_table[(size_t)r*64 + k], lw[(64 + k)*64 + j], acc);
  relb[j] = acc;
  float heur = acc;
  for (int k = 0; k < 64; k++) heur = fmaf(hs[b*64 + k], lw[k*64 + j], heur);
  float x = hs[b*64 + j] * heur;
  float o = 0.f;
  for (int half = 0; half < 2; half++){
    float a = b1[half*64 + j];
    for (int k = 0; k < 64; k++) a = fmaf(__shfl(x, k), w1[k*128 + half*64 + j], a);
    o = fmaf(fmaxf(a, 0.f), w2[half*64 + j], o);
  }
  o = waveSumF(o);
  if (j == 0) stF[7] = o + b2[0];
}

__global__ void k_inithidden(unsigned* WB, long sb, int b0,
                             const int* __restrict__ lastm, const float* __restrict__ ste,
                             const float* __restrict__ hs, const int* __restrict__ h_index){
  BBASE;
  float4* hidden = (float4*)(B + OFF_HID);
  const float4* ste4 = (const float4*)ste;
  const float4* hs4  = (const float4*)hs;
  int b = b0 + blockIdx.y;
  int idx = blockIdx.x * 256 + threadIdx.x;     // grid covers NN*16 exactly
  int n = idx >> 4, j = idx & 15;
  int h = h_index[b];
  float4 v = make_float4(0.f, 0.f, 0.f, 0.f);
  int lm = lastm[n];
  if (lm >= 0) v = ste4[(size_t)lm*16 + j];
  if (n == h)  v = hs4[b*16 + j];
  hidden[idx] = v;
}

__global__ void k_initscore(unsigned* WB, long sb, int b0,
                            const int* __restrict__ h_index, const float* __restrict__ gstF){
  BBASE;
  float* score = (float*)(B + OFF_SCORE);
  unsigned* st = B + OFF_ST;
  float* stF = (float*)st;
  int b = b0 + blockIdx.y;
  int i = blockIdx.x * 256 + threadIdx.x;
  if (i < NN) score[i] = (i == h_index[b]) ? stF[7] : gstF[6];
  if (i == 0){ st[0] = 0u; st[1] = KSEL; }
}

// ------------------------------ top-k machinery -----------------------------

// node histogram (unweighted): 2 leader rounds -> LDS hash -> single-plane flush
__global__ __launch_bounds__(256) void k_hist(unsigned* WB, long sb, int pass){
  BBASE;
  const unsigned* st = B + OFF_ST;
  const float* score = (const float*)(B + OFF_SCORE);
  unsigned* hist = B + ((pass == 1) ? OFF_HISTA : OFF_HISTB);
  __shared__ unsigned hkey[512];
  __shared__ unsigned hval[512];
  for (int t = threadIdx.x; t < 512; t += 256){ hkey[t] = 0xFFFFFFFFu; hval[t] = 0u; }
  __syncthreads();
  int i = blockIdx.x * 256 + threadIdx.x;
  unsigned bin = 0xFFFFFFFFu;
  if (i < NN){
    unsigned k = fkey(score[i]);
    if (pass == 1) bin = k >> 16;
    else if ((k >> 16) == (st[0] >> 16)) bin = k & 0xFFFFu;
  }
  bool active = (bin != 0xFFFFFFFFu);
  int lane = threadIdx.x & 63;
  #pragma unroll
  for (int r = 0; r < 2; r++){
    unsigned long long mask = __ballot((int)active);
    if (mask != 0ull){
      int leader = __ffsll(mask) - 1;
      unsigned lbin = (unsigned)__shfl((int)bin, leader);
      bool same = active && (bin == lbin);
      unsigned long long smask = __ballot((int)same);
      if (lane == leader) ldsHashAdd(hkey, hval, lbin, (unsigned)__popcll(smask));
      if (same) active = false;
    }
  }
  if (active) ldsHashAdd(hkey, hval, bin, 1u);
  __syncthreads();
  for (int t = threadIdx.x; t < 512; t += 256){
    unsigned vv = hval[t];
    if (vv) atomicAdd(hist + hkey[t], vv);
  }
}

// in-degree (from selected sources) accumulation into CURS + st reset
__global__ void k_indegW(unsigned* WB, long sb,
                         const int* __restrict__ esrc, const int* __restrict__ edst){
  BBASE;
  unsigned* st = B + OFF_ST;
  const unsigned* nsel = B + OFF_NSEL;
  unsigned* indeg = B + OFF_CURS;
  int i = blockIdx.x * 256 + threadIdx.x;
  if (i < NEG && nsel[esrc[i]]) atomicAdd(indeg + edst[i], 1u);
  if (i == 0){ st[0] = 0u; st[1] = ESEL; st[2] = 0u; st[3] = 0u; st[4] = 0u; st[5] = 0u; }
}

// weighted node histogram for the edge top-ESEL (weight = indeg)
__global__ __launch_bounds__(256) void k_histW(unsigned* WB, long sb, int pass){
  BBASE;
  const unsigned* st = B + OFF_ST;
  const unsigned* indeg = B + OFF_CURS;
  const float* score = (const float*)(B + OFF_SCORE);
  unsigned* hist = B + ((pass == 1) ? OFF_HISTA : OFF_HISTB);
  __shared__ unsigned hkey[512];
  __shared__ unsigned hval[512];
  for (int t = threadIdx.x; t < 512; t += 256){ hkey[t] = 0xFFFFFFFFu; hval[t] = 0u; }
  __syncthreads();
  int i = blockIdx.x * 256 + threadIdx.x;
  unsigned w = (i < NN) ? indeg[i] : 0u;
  if (w){
    unsigned k = fkey(score[i]);
    unsigned bin = 0xFFFFFFFFu;
    if (pass == 1) bin = k >> 16;
    else if ((k >> 16) == (st[0] >> 16)) bin = k & 0xFFFFu;
    if (bin != 0xFFFFFFFFu) ldsHashAdd(hkey, hval, bin, w);
  }
  __syncthreads();
  for (int t = threadIdx.x; t < 512; t += 256){
    unsigned vv = hval[t];
    if (vv) atomicAdd(hist + hkey[t], vv);
  }
}

// single block per batch: find digit containing the R-th largest; update st.
__global__ __launch_bounds__(1024) void k_pick16(unsigned* WB, long sb, int pass){
  BBASE;
  unsigned* st = B + OFF_ST;
  const unsigned* hist = B + ((pass == 1) ? OFF_HISTA : OFF_HISTB);
  __shared__ unsigned csum[1024];
  __shared__ unsigned sc[1024];
  int t = threadIdx.x;
  unsigned R = st[1];
  unsigned s = 0;
  {
    const unsigned* hp = hist + (unsigned)t * 64u;
    for (int b = 0; b < 64; b++) s += hp[b];
  }
  csum[t] = s; sc[t] = s; __syncthreads();
  for (int d = 1; d < 1024; d <<= 1){
    unsigned v = (t >= d) ? sc[t - d] : 0u;
    __syncthreads();
    sc[t] += v;
    __syncthreads();
  }
  unsigned total = sc[1023];
  unsigned above = total - sc[t];               // keys in higher chunks
  unsigned cs = csum[t];
  if (above < R && above + cs >= R){
    unsigned cum = above;
    for (int b = 63; b >= 0; b--){
      unsigned c = hist[(unsigned)(t*64 + b)];
      if (cum + c >= R){
        unsigned bstar = (unsigned)(t*64 + b);
        if (pass == 1) st[0] = bstar << 16; else st[0] = st[0] | bstar;
        st[1] = R - cum;
        break;
      }
      cum += c;
    }
  }
  if (t == 0 && total < R){                     // threshold lands in -inf bin
    if (pass == 1) st[0] = KEY_NEG_INF & 0xFFFF0000u;
    else           st[0] = st[0] | 0xFFFFu;
    st[1] = R - total;
  }
}

// per-block counts of (eq, gt) vs threshold; zeroes hist buffers AND dcnt.
// mode 0: node keys. mode 1: edge keys recomputed on the fly.
__global__ __launch_bounds__(1024) void k_countEq(unsigned* WB, long sb, int mode, int n,
                                                  const int* __restrict__ esrc,
                                                  const int* __restrict__ edst){
  BBASE;
  unsigned* hz = B + OFF_HISTA;                  // A+B contiguous: 131072 u32
  for (unsigned j = blockIdx.x * 1024u + threadIdx.x; j < 131072u; j += gridDim.x * 1024u)
    hz[j] = 0u;
  unsigned* dcnt = B + OFF_DCNT;
  const unsigned* st = B + OFF_ST;
  const unsigned* nsel = B + OFF_NSEL;
  const float* score = (const float*)(B + OFF_SCORE);
  unsigned* bcE = B + OFF_BC;
  unsigned* bcG = B + OFF_BC2;
  int i = blockIdx.x * 1024 + threadIdx.x;
  if (i < NN) dcnt[i] = 0u;
  unsigned v = st[0];
  unsigned k = 0u;
  if (i < n){
    if (mode) k = nsel[esrc[i]] ? fkey(score[edst[i]]) : KEY_NEG_INF;
    else      k = fkey(score[i]);
  }
  bool eq = (i < n) && (k == v);
  bool gt = (i < n) && (k > v);
  unsigned long long ebal = __ballot((int)eq);
  unsigned long long gbal = __ballot((int)gt);
  __shared__ unsigned wshE[16];
  __shared__ unsigned wshG[16];
  int wid = threadIdx.x >> 6, lane = threadIdx.x & 63;
  if (lane == 0){ wshE[wid] = (unsigned)__popcll(ebal); wshG[wid] = (unsigned)__popcll(gbal); }
  __syncthreads();
  if (threadIdx.x == 0){
    unsigned te = 0, tg = 0;
    for (int w = 0; w < 16; w++){ te += wshE[w]; tg += wshG[w]; }
    bcE[blockIdx.x] = te; bcG[blockIdx.x] = tg;
  }
}

__global__ __launch_bounds__(1024) void k_scanBlocks(unsigned* WB, long sb, int nbk){
  BBASE;
  unsigned* blockcnt = B + OFF_BC;
  __shared__ unsigned sc[2048];
  int t = threadIdx.x;
  unsigned a  = (t < nbk) ? blockcnt[t] : 0u;
  unsigned b2 = (1024 + t < nbk) ? blockcnt[1024 + t] : 0u;
  sc[t] = a; sc[1024 + t] = b2; __syncthreads();
  for (int d = 1; d < 2048; d <<= 1){
    unsigned v1 = (t >= d) ? sc[t - d] : 0u;
    unsigned v2 = (1024 + t >= d) ? sc[1024 + t - d] : 0u;
    __syncthreads();
    sc[t] += v1; sc[1024 + t] += v2;
    __syncthreads();
  }
  if (t < nbk) blockcnt[t] = sc[t] - a;             // exclusive
  if (1024 + t < nbk) blockcnt[1024 + t] = sc[1024 + t] - b2;
}

// dual scan (eq + gt) for edge compaction; also computes st[2], st[4]
__global__ __launch_bounds__(1024) void k_scanBlocks2(unsigned* WB, long sb, int nbk){
  BBASE;
  unsigned* st = B + OFF_ST;
  unsigned* bcE = B + OFF_BC;
  unsigned* bcG = B + OFF_BC2;
  __shared__ unsigned se[2048];
  __shared__ unsigned sg[2048];
  int t = threadIdx.x;
  unsigned e0 = (t < nbk) ? bcE[t] : 0u;
  unsigned e1 = (1024 + t < nbk) ? bcE[1024 + t] : 0u;
  unsigned g0 = (t < nbk) ? bcG[t] : 0u;
  unsigned g1 = (1024 + t < nbk) ? bcG[1024 + t] : 0u;
  se[t] = e0; se[1024 + t] = e1; sg[t] = g0; sg[1024 + t] = g1;
  __syncthreads();
  for (int d = 1; d < 2048; d <<= 1){
    unsigned a1 = (t >= d) ? se[t - d] : 0u;
    unsigned a2 = (1024 + t >= d) ? se[1024 + t - d] : 0u;
    unsigned c1 = (t >= d) ? sg[t - d] : 0u;
    unsigned c2 = (1024 + t >= d) ? sg[1024 + t - d] : 0u;
    __syncthreads();
    se[t] += a1; se[1024 + t] += a2; sg[t] += c1; sg[1024 + t] += c2;
    __syncthreads();
  }
  if (t < nbk) bcE[t] = se[t] - e0;
  if (1024 + t < nbk) bcE[1024 + t] = se[1024 + t] - e1;
  if (t < nbk) bcG[t] = sg[t] - g0;
  if (1024 + t < nbk) bcG[1024 + t] = sg[1024 + t] - g1;
  if (t == 0){
    unsigned gtTot = sg[2047];
    st[4] = gtTot;
    st[2] = gtTot + ((st[0] > KEY_NEG_INF) ? st[1] : 0u);  // R' <= eqTot always
  }
}

// node selection; also zeroes CURS (used as indeg accumulator next)
__global__ __launch_bounds__(1024) void k_selNodes(unsigned* WB, long sb){
  BBASE;
  const unsigned* st = B + OFF_ST;
  const unsigned* blockcnt = B + OFF_BC;
  const float* score = (const float*)(B + OFF_SCORE);
  unsigned* nsel = B + OFF_NSEL;
  unsigned* curs = B + OFF_CURS;
  int i = blockIdx.x * 1024 + threadIdx.x;
  if (i < NN) curs[i] = 0u;
  unsigned v = st[0], R = st[1];
  unsigned k = (i < NN) ? fkey(score[i]) : 0u;
  bool eq = (i < NN) && (k == v);
  unsigned long long bal = __ballot((int)eq);
  __shared__ unsigned wsh[16];
  int wid = threadIdx.x >> 6, lane = threadIdx.x & 63;
  if (lane == 0) wsh[wid] = (unsigned)__popcll(bal);
  __syncthreads();
  unsigned woff = 0;
  for (int w = 0; w < wid; w++) woff += wsh[w];
  unsigned lpre = (unsigned)__popcll(bal & ((1ull << lane) - 1ull));
  unsigned rank = blockcnt[blockIdx.x] + woff + lpre;
  if (i < NN) nsel[i] = (k > v || (eq && rank < R)) ? 1u : 0u;
}

// scan-based edge compaction (keys recomputed; deterministic);
// accumulates dcnt[dst] for taken edges (dcnt zeroed by k_countEq)
__global__ __launch_bounds__(1024) void k_selEdgesCompact(unsigned* WB, long sb,
                                                          const int* __restrict__ esrc,
                                                          const int* __restrict__ edst){
  BBASE;
  const unsigned* st = B + OFF_ST;
  const unsigned* bcE = B + OFF_BC;
  const unsigned* bcG = B + OFF_BC2;
  const unsigned* nsel = B + OFF_NSEL;
  const float* score = (const float*)(B + OFF_SCORE);
  unsigned* elist = B + OFF_ELIST;
  unsigned* dcnt = B + OFF_DCNT;
  int i = blockIdx.x * 1024 + threadIdx.x;
  unsigned v = st[0], R = st[1], gtTot = st[4];
  unsigned k = 0u;
  if (i < NEG) k = nsel[esrc[i]] ? fkey(score[edst[i]]) : KEY_NEG_INF;
  bool eq = (i < NEG) && (k == v);
  bool gt = (i < NEG) && (k > v);                   // gt implies finite key
  unsigned long long ebal = __ballot((int)eq);
  unsigned long long gbal = __ballot((int)gt);
  __shared__ unsigned wshE[16];
  __shared__ unsigned wshG[16];
  int wid = threadIdx.x >> 6, lane = threadIdx.x & 63;
  if (lane == 0){ wshE[wid] = (unsigned)__popcll(ebal); wshG[wid] = (unsigned)__popcll(gbal); }
  __syncthreads();
  unsigned eoff = 0, goff = 0;
  for (int w = 0; w < 16 && w < wid; w++){ eoff += wshE[w]; goff += wshG[w]; }
  unsigned long long ltm = (1ull << lane) - 1ull;
  if (gt){
    elist[bcG[blockIdx.x] + goff + (unsigned)__popcll(gbal & ltm)] = (unsigned)i;
    atomicAdd(dcnt + edst[i], 1u);
  }
  if (eq){
    unsigned rank = bcE[blockIdx.x] + eoff + (unsigned)__popcll(ebal & ltm);
    if (v > KEY_NEG_INF && rank < R){
      elist[gtTot + rank] = (unsigned)i;
      atomicAdd(dcnt + edst[i], 1u);
    }
  }
}

// ------------------------------- CSR build ----------------------------------

__global__ __launch_bounds__(1024) void k_blocksumsInt(unsigned* WB, long sb){
  BBASE;
  const unsigned* dcnt = B + OFF_DCNT;
  unsigned* blockcnt = B + OFF_BC;
  int i = blockIdx.x * 1024 + threadIdx.x;
  unsigned v = (i < NN) ? dcnt[i] : 0u;
  #pragma unroll
  for (int d = 1; d < 64; d <<= 1) v += (unsigned)__shfl_xor((int)v, d);
  __shared__ unsigned wsh[16];
  int wid = threadIdx.x >> 6, lane = threadIdx.x & 63;
  if (lane == 0) wsh[wid] = v;
  __syncthreads();
  if (threadIdx.x == 0){
    unsigned tot = 0;
    for (int w = 0; w < 16; w++) tot += wsh[w];
    blockcnt[blockIdx.x] = tot;
  }
}

// row starts + cursor + ACTIVE list + source snapshot (merged)
__global__ __launch_bounds__(1024) void k_rowSnap(unsigned* WB, long sb){
  BBASE;
  unsigned* st = B + OFF_ST;
  const unsigned* dcnt = B + OFF_DCNT;
  const unsigned* blockcnt = B + OFF_BC;
  unsigned* rowstart = B + OFF_ROWS;
  unsigned* curs = B + OFF_CURS;
  unsigned* actl = B + OFF_ACT;
  unsigned* srcmap = B + OFF_NSEL;
  const float* score = (const float*)(B + OFF_SCORE);
  const float* hidden = (const float*)(B + OFF_HID);
  float* srch = (float*)(B + OFF_SRCH);
  int i = blockIdx.x * 1024 + threadIdx.x;
  int wid = threadIdx.x >> 6, lane = threadIdx.x & 63;
  unsigned d = (i < NN) ? dcnt[i] : 0u;
  unsigned v = d;
  #pragma unroll
  for (int dl = 1; dl < 64; dl <<= 1){
    unsigned t2 = (unsigned)__shfl_up((int)v, dl);
    if (lane >= dl) v += t2;
  }
  bool act = (i < NN) && (d > 0u);
  unsigned long long abal = __ballot((int)act);
  __shared__ unsigned wsh[16];
  __shared__ unsigned awsh[16];
  __shared__ unsigned abase;
  if (lane == 63) wsh[wid] = v;
  if (lane == 0) awsh[wid] = (unsigned)__popcll(abal);
  __syncthreads();
  if (threadIdx.x == 0){
    unsigned tot = 0;
    for (int w = 0; w < 16; w++) tot += awsh[w];
    abase = atomicAdd(st + 3, tot);
  }
  unsigned woff = 0, aoff = 0;
  for (int w = 0; w < wid; w++){ woff += wsh[w]; aoff += awsh[w]; }
  __syncthreads();
  unsigned excl = blockcnt[blockIdx.x] + woff + (v - d);
  if (i < NN){ rowstart[i] = excl; curs[i] = excl; }
  if (act) actl[abase + aoff + (unsigned)__popcll(abal & ((1ull << lane) - 1ull))] = (unsigned)i;

  // ---- snap part: each wave handles its 64 nodes (disjoint arrays above)
  int base = i - lane;                        // wave's node base
  if (base >= NN) return;
  bool sel = (i < NN) && (srcmap[i] != 0u);
  unsigned long long bal = __ballot((int)sel);
  if (bal == 0ull) return;
  unsigned slotbase = 0;
  if (lane == 0) slotbase = atomicAdd(st + 5, (unsigned)__popcll(bal));
  slotbase = (unsigned)__shfl((int)slotbase, 0);
  unsigned long long m2 = bal;
  unsigned idx = 0;
  while (m2){
    int j = __ffsll(m2) - 1;
    m2 = m2 - (m2 bitand (0ull - m2));        // clear lowest set bit (entity-safe)
    int node = base + j;
    unsigned slot = slotbase + idx; idx++;
    if (lane == 0) srcmap[node] = slot;
    float g = 1.f / (1.f + expf(-score[node]));   // same formula as before
    srch[(size_t)slot*64 + lane] = g * hidden[(size_t)node*64 + lane];
  }
}

// scatter packed (slot<<10)|etype into CSR (needs srcmap from k_rowSnap)
__global__ void k_scatter(unsigned* WB, long sb, const int* __restrict__ esrc,
                          const int* __restrict__ edst, const int* __restrict__ etype){
  BBASE;
  const unsigned* st = B + OFF_ST;
  const unsigned* elist = B + OFF_ELIST;
  const unsigned* srcmap = B + OFF_NSEL;
  unsigned* curs = B + OFF_CURS;
  unsigned* csr = B + OFF_CSR;
  unsigned i = blockIdx.x * 256 + threadIdx.x;
  if (i < st[2]){
    unsigned e = elist[i];
    unsigned slot = srcmap[esrc[e]];
    unsigned pk = (slot << 10) | (unsigned)etype[e];
    unsigned pos = atomicAdd(curs + edst[e], 1u);
    csr[pos] = pk;
  }
}

// --------------------- fused aggregation + PNA update -----------------------

__global__ __launch_bounds__(256) void k_aggpna(unsigned* WB, long sb,
    const float* __restrict__ relw, const float* __restrict__ pw,
    const float* __restrict__ pb, const float* __restrict__ gstF, int l){
  BBASE;
  const unsigned* st = B + OFF_ST;
  const unsigned* actl = B + OFF_ACT;
  const unsigned* dcnt = B + OFF_DCNT;
  const unsigned* rows = B + OFF_ROWS;
  const unsigned* csr = B + OFF_CSR;
  const float* srch = (const float*)(B + OFF_SRCH);
  float* hidden = (float*)(B + OFF_HID);
  const float* relw_l = relw + (size_t)l * NR2 * 64;
  const float* pw_l = pw + (size_t)l * 768 * 64;

  int wv = (blockIdx.x * 256 + threadIdx.x) >> 6;
  int lane = threadIdx.x & 63;
  unsigned nact = st[3];
  unsigned slot0 = (unsigned)wv * 8u;
  if (slot0 >= nact) return;

  int node[8];
  float aggm[8], aggx[8], aggn[8], aggs[8];   // mean, max, min, std
  float ampv[8], attv[8];
  #pragma unroll
  for (int n = 0; n < 8; n++){
    unsigned s = slot0 + (unsigned)n;
    node[n] = (s < nact) ? (int)actl[s] : -1;
  }
  float dmean = gstF[5];
  #pragma unroll
  for (int n = 0; n < 8; n++){
    float sm_ = 0.f, sq_ = 0.f;
    float mx_ = -__builtin_huge_valf(), mn_ = __builtin_huge_valf();
    float dv = 0.f;
    if (node[n] >= 0){
      unsigned cnt = dcnt[node[n]], rs = rows[node[n]];
      dv = (float)cnt;
      for (unsigned ii = 0; ii < cnt; ii++){
        unsigned pk = csr[rs + ii];
        float m = srch[(size_t)(pk >> 10)*64 + lane] * relw_l[(size_t)(pk & 1023u)*64 + lane];
        sm_ += m; sq_ = fmaf(m, m, sq_);
        mx_ = fmaxf(mx_, m); mn_ = fminf(mn_, m);
      }
    }
    if (node[n] >= 0){
      float degc = fmaxf(dv, 1.f);
      float me = sm_ / degc;
      float qv = sq_ / degc;
      aggm[n] = me;
      aggs[n] = sqrtf(fmaxf(qv - me*me, 0.f) + 1e-6f);
      aggx[n] = mx_; aggn[n] = mn_;
      float logd = logf(dv + 1.f);
      ampv[n] = logd / dmean;
      attv[n] = dmean / fmaxf(logd, 1e-6f);
    } else { aggm[n] = 0.f; aggs[n] = 0.f; aggx[n] = 0.f; aggn[n] = 0.f; ampv[n] = 0.f; attv[n] = 0.f; }
  }
  float bias = pb[(size_t)l*64 + lane];
  float acc[8];
  #pragma unroll
  for (int n = 0; n < 8; n++) acc[n] = bias;
  for (int c = 0; c < 12; c++){
    int a = c / 3, s = c - a*3;
    float wreg[64];
    #pragma unroll
    for (int k = 0; k < 64; k++) wreg[k] = pw_l[(size_t)(c*64 + k)*64 + lane];
    float fv[8];
    #pragma unroll
    for (int n = 0; n < 8; n++){
      float v = 0.f;
      if (node[n] >= 0){
        if (a == 0)      v = aggm[n];
        else if (a == 1) v = aggx[n];
        else if (a == 2) v = aggn[n];
        else             v = aggs[n];
        float scaler = (s == 0) ? 1.f : ((s == 1) ? ampv[n] : attv[n]);
        v *= scaler;
      }
      fv[n] = v;
    }
    #pragma unroll
    for (int k = 0; k < 64; k++){
      float w = wreg[k];
      #pragma unroll
      for (int n = 0; n < 8; n++) acc[n] = fmaf(RL(fv[n], k), w, acc[n]);
    }
  }
  #pragma unroll
  for (int n = 0; n < 8; n++)
    if (node[n] >= 0) hidden[(size_t)node[n]*64 + lane] += acc[n];
}

// ------------------------- rescore active nodes -----------------------------

__global__ __launch_bounds__(256) void k_scoreK(unsigned* WB, long sb,
    const float* __restrict__ lw, const float* __restrict__ w1,
    const float* __restrict__ b1, const float* __restrict__ w2,
    const float* __restrict__ b2){
  BBASE;
  unsigned* st = B + OFF_ST;
  if (blockIdx.x == 0 && threadIdx.x == 0){ st[0] = 0u; st[1] = KSEL; }  // next node topk
  const unsigned* actl = B + OFF_ACT;
  const float* hidden = (const float*)(B + OFF_HID);
  const float* relb = (const float*)(B + OFF_RELB);
  float* score = (float*)(B + OFF_SCORE);
  unsigned nact = st[3];
  int wv = (blockIdx.x * 256 + threadIdx.x) >> 6;
  int lane = threadIdx.x & 63;
  unsigned slot0 = (unsigned)wv * 8u;
  if (slot0 >= nact) return;
  int node[8];
  #pragma unroll
  for (int n = 0; n < 8; n++){
    unsigned s = slot0 + (unsigned)n;
    node[n] = (s < nact) ? (int)actl[s] : -1;
  }
  float wreg[64];
  #pragma unroll
  for (int k = 0; k < 64; k++) wreg[k] = lw[k*64 + lane];
  float relbv = relb[lane];
  float hidv[8];
  #pragma unroll
  for (int n = 0; n < 8; n++)
    hidv[n] = (node[n] >= 0) ? hidden[(size_t)node[n]*64 + lane] : 0.f;
  float hv[8];
  #pragma unroll
  for (int n = 0; n < 8; n++) hv[n] = relbv;
  #pragma unroll
  for (int k = 0; k < 64; k++){
    float w = wreg[k];
    #pragma unroll
    for (int n = 0; n < 8; n++) hv[n] = fmaf(RL(hidv[n], k), w, hv[n]);
  }
  float xv[8];
  #pragma unroll
  for (int n = 0; n < 8; n++) xv[n] = hidv[n] * hv[n];
  float outv[8];
  #pragma unroll
  for (int n = 0; n < 8; n++) outv[n] = 0.f;
  for (int half = 0; half < 2; half++){
    #pragma unroll
    for (int k = 0; k < 64; k++) wreg[k] = w1[k*128 + half*64 + lane];
    float a[8];
    float b1l = b1[half*64 + lane];
    #pragma unroll
    for (int n = 0; n < 8; n++) a[n] = b1l;
    #pragma unroll
    for (int k = 0; k < 64; k++){
      float w = wreg[k];
      #pragma unroll
      for (int n = 0; n < 8; n++) a[n] = fmaf(RL(xv[n], k), w, a[n]);
    }
    float w2l = w2[half*64 + lane];
    #pragma unroll
    for (int n = 0; n < 8; n++) outv[n] = fmaf(fmaxf(a[n], 0.f), w2l, outv[n]);
  }
  float b2v = b2[0];
  #pragma unroll
  for (int n = 0; n < 8; n++){
    float r = waveSumF(outv[n]);
    if (lane == 0 && node[n] >= 0) score[node[n]] = r + b2v;
  }
}

__global__ void k_out(unsigned* WB, long sb, int b0,
                      const int* __restrict__ t_index, float* __restrict__ out){
  BBASE;
  const float* score = (const float*)(B + OFF_SCORE);
  int b = b0 + blockIdx.y;
  int t = threadIdx.x;
  if (t < NTC) out[b*NTC + t] = score[t_index[b*NTC + t]];
}

// ------------------------------- launcher -----------------------------------

extern "C" void kernel_launch(void* const* d_in, const int* in_sizes, int n_in,
                              void* d_out, int out_size, void* d_ws, size_t ws_size,
                              hipStream_t stream){
  (void)in_sizes; (void)n_in; (void)out_size;
  const int*   h_index  = (const int*)d_in[0];
  const int*   r_index  = (const int*)d_in[1];
  const int*   t_index  = (const int*)d_in[2];
  const int*   all_idx  = (const int*)d_in[3];
  const int*   esrc     = (const int*)d_in[4];
  const int*   edst     = (const int*)d_in[5];
  const int*   etype    = (const int*)d_in[6];
  const float* hs       = (const float*)d_in[7];
  const float* ste      = (const float*)d_in[8];
  const float* rel_tab  = (const float*)d_in[9];
  const float* lw       = (const float*)d_in[10];
  const float* lb       = (const float*)d_in[11];
  const float* w1       = (const float*)d_in[12];
  const float* b1       = (const float*)d_in[13];
  const float* w2       = (const float*)d_in[14];
  const float* b2       = (const float*)d_in[15];
  const float* relw     = (const float*)d_in[16];
  const float* pna_w    = (const float*)d_in[17];
  const float* pna_b    = (const float*)d_in[18];
  float* out = (float*)d_out;

  unsigned* W = (unsigned*)d_ws;
  int*      LASTM = (int*)W;                    // 50000
  unsigned* DEGF  = W + 50000;                  // 50000
  float*    GSTF  = (float*)(W + 100000);       // 64
  unsigned* WB    = W + 100064;                 // batch blocks

  size_t needB = (size_t)(100064 + 4*(size_t)SBLK) * 4u;
  int nb; long sb; int nseq;
  if (ws_size >= needB){ nb = 4; sb = SBLK; nseq = 1; }
  else                 { nb = 1; sb = 0;    nseq = 4; }

  (void)hipMemsetAsync(W + 100000, 0, 64 * 4, stream);          // GSTF
  (void)hipMemsetAsync(LASTM, 0xFF, NN * 4, stream);
  (void)hipMemsetAsync(DEGF, 0, NN * 4, stream);
  for (int q = 0; q < nb; q++)
    (void)hipMemsetAsync(WB + (size_t)q*SBLK + OFF_HISTA, 0, 131072 * 4, stream);

  const int GB_E256  = (NEG + 255) / 256;       // 6250
  const int GB_N256  = (NN + 255) / 256;        // 196
  const int GB_N1024 = (NN + 1023) / 1024;      // 49
  const int GB_E1024 = (NEG + 1023) / 1024;     // 1563
  const int GB_H4    = (NN * 16) / 256;         // 3125 (float4 rows)
  const int GB_A     = 1563;                    // 4 waves x 8 slots covers 50016
  const int GB_ES    = (int)(ESEL / 256);       // 625

  k_lastm<<<(NMI + 255) / 256, 256, 0, stream>>>(all_idx, LASTM);
  k_degfull<<<GB_E256, 256, 0, stream>>>(esrc, DEGF);
  k_dsum<<<GB_N256, 256, 0, stream>>>(DEGF, GSTF);
  k_finalize<<<1, 1, 0, stream>>>(GSTF, b1, w2, b2);

  for (int q = 0; q < nseq; q++){
    int b0 = (nb == 4) ? 0 : q;
    k_relb<<<dim3(1, nb), 64, 0, stream>>>(WB, sb, b0, r_index, hs, rel_tab, lw, lb, w1, b1, w2, b2);
    k_inithidden<<<dim3(GB_H4, nb), 256, 0, stream>>>(WB, sb, b0, LASTM, ste, hs, h_index);
    k_initscore<<<dim3(GB_N256, nb), 256, 0, stream>>>(WB, sb, b0, h_index, GSTF);

    for (int l = 0; l < 3; l++){
      // ---- node top-K
      k_hist<<<dim3(GB_N256, nb), 256, 0, stream>>>(WB, sb, 1);
      k_pick16<<<dim3(1, nb), 1024, 0, stream>>>(WB, sb, 1);
      k_hist<<<dim3(GB_N256, nb), 256, 0, stream>>>(WB, sb, 0);
      k_pick16<<<dim3(1, nb), 1024, 0, stream>>>(WB, sb, 0);
      k_countEq<<<dim3(GB_N1024, nb), 1024, 0, stream>>>(WB, sb, 0, NN, esrc, edst);
      k_scanBlocks<<<dim3(1, nb), 1024, 0, stream>>>(WB, sb, GB_N1024);
      k_selNodes<<<dim3(GB_N1024, nb), 1024, 0, stream>>>(WB, sb);      // + zeroes CURS
      // ---- edge top-ESEL as weighted node top-k
      k_indegW<<<dim3(GB_E256, nb), 256, 0, stream>>>(WB, sb, esrc, edst);
      k_histW<<<dim3(GB_N256, nb), 256, 0, stream>>>(WB, sb, 1);
      k_pick16<<<dim3(1, nb), 1024, 0, stream>>>(WB, sb, 1);
      k_histW<<<dim3(GB_N256, nb), 256, 0, stream>>>(WB, sb, 0);
      k_pick16<<<dim3(1, nb), 1024, 0, stream>>>(WB, sb, 0);
      k_countEq<<<dim3(GB_E1024, nb), 1024, 0, stream>>>(WB, sb, 1, NEG, esrc, edst);
      k_scanBlocks2<<<dim3(1, nb), 1024, 0, stream>>>(WB, sb, GB_E1024);
      k_selEdgesCompact<<<dim3(GB_E1024, nb), 1024, 0, stream>>>(WB, sb, esrc, edst);
      // ---- CSR rows + active compaction + snapshot (merged) + scatter
      k_blocksumsInt<<<dim3(GB_N1024, nb), 1024, 0, stream>>>(WB, sb);
      k_scanBlocks<<<dim3(1, nb), 1024, 0, stream>>>(WB, sb, GB_N1024);
      k_rowSnap<<<dim3(GB_N1024, nb), 1024, 0, stream>>>(WB, sb);
      k_scatter<<<dim3(GB_ES, nb), 256, 0, stream>>>(WB, sb, esrc, edst, etype);
      // ---- fused aggregate + PNA update, then rescore
      k_aggpna<<<dim3(GB_A, nb), 256, 0, stream>>>(WB, sb, relw, pna_w, pna_b, GSTF, l);
      k_scoreK<<<dim3(GB_A, nb), 256, 0, stream>>>(WB, sb, lw, w1, b1, w2, b2);
    }
    k_out<<<dim3(1, nb), 32, 0, stream>>>(WB, sb, b0, t_index, out);
  }
}